// Round 3
// baseline (797.005 us; speedup 1.0000x reference)
//
#include <hip/hip_runtime.h>
#include <math.h>

// clDice loss, fully fused (R3).
// Key insight: skel after 10 iterations at a tile needs only halo-12 of the
// original image (erode chain grows halo 1/iter, +2 for final open; skel
// update is pointwise), and only SUMS of the skeletons are needed.
// => one mega-kernel: load logits+target tile+halo12, sigmoid, run init + 10
// morphology iterations entirely in LDS, keep skel in registers, write 6
// per-block partial sums. Global traffic ~64MB reads / ~200KB writes total
// (was ~2.7GB), 2 launches (was 25).

#define HH 1024
#define WW 1024
#define BATCH 8
#define HW (HH * WW)
#define NITER 10
#define TW 64
#define TH 16
#define HALO 12
#define IW (TW + 2 * HALO)  // 88
#define IH (TH + 2 * HALO)  // 40
#define NCELL (IH * IW)     // 3520
#define NBX (WW / TW)       // 16
#define NBY (HH / TH)       // 64
#define NBLK (NBX * NBY * BATCH)  // 8192

// erode over shrinking region [it, IH-it) x [it, IW-it); out-of-image -> +inf
__device__ __forceinline__ void erode_shrink(const float* __restrict__ src,
                                             float* __restrict__ dst,
                                             int it, int y0, int x0) {
    for (int li = threadIdx.x; li < NCELL; li += 256) {
        int r = li / IW, c = li - r * IW;
        if (r < it || r >= IH - it || c < it || c >= IW - it) continue;
        int gy = y0 - HALO + r, gx = x0 - HALO + c;
        float v;
        if ((unsigned)gy < HH && (unsigned)gx < WW) {
            const float* p = src + li;
            v = fminf(fminf(fminf(p[-1], p[1]), p[0]), fminf(p[-IW], p[IW]));
        } else v = INFINITY;
        dst[li] = v;
    }
}

// erode over fixed region [11,29) x [11,77) (tile+1); out-of-image -> -inf
// (this output feeds the dilate)
__device__ __forceinline__ void erode_inner(const float* __restrict__ src,
                                            float* __restrict__ dst,
                                            int y0, int x0) {
    for (int li = threadIdx.x; li < 18 * 66; li += 256) {
        int r = 11 + li / 66, c = 11 + li % 66;
        int idx = r * IW + c;
        int gy = y0 - HALO + r, gx = x0 - HALO + c;
        float v;
        if ((unsigned)gy < HH && (unsigned)gx < WW) {
            const float* p = src + idx;
            v = fminf(fminf(fminf(p[-1], p[1]), p[0]), fminf(p[-IW], p[IW]));
        } else v = -INFINITY;
        dst[idx] = v;
    }
}

// open = dilate3x3(e2) at this thread's 4 tile cells; delta = relu(im - open)
__device__ __forceinline__ void open_delta(const float* __restrict__ e2,
                                           const float* __restrict__ im,
                                           int orow, int oc, float delta[4]) {
    int r0 = HALO + orow, c0 = HALO + oc;
    const float* up = e2 + (r0 - 1) * IW + (c0 - 1);
    const float* md = e2 + r0 * IW + (c0 - 1);
    const float* dn = e2 + (r0 + 1) * IW + (c0 - 1);
    float cm[6];
#pragma unroll
    for (int cc = 0; cc < 6; ++cc) cm[cc] = fmaxf(fmaxf(up[cc], md[cc]), dn[cc]);
    const float* imr = im + r0 * IW + c0;
#pragma unroll
    for (int k = 0; k < 4; ++k) {
        float open = fmaxf(fmaxf(cm[k], cm[k + 1]), cm[k + 2]);
        delta[k] = fmaxf(imr[k] - open, 0.0f);
    }
}

__global__ __launch_bounds__(256) void cldice_mega_kernel(const float* __restrict__ logits,
                                                          const int* __restrict__ target,
                                                          float* __restrict__ partials) {
    __shared__ float bufA[NCELL];
    __shared__ float bufB[NCELL];
    __shared__ float red[24];

    int img = blockIdx.z;
    int x0 = blockIdx.x * TW, y0 = blockIdx.y * TH;
    int tid = threadIdx.x;
    int orow = tid >> 4, oc = (tid & 15) * 4;

    float p4[4];        // probs at my 4 tile cells (phase 0)
    float skO[4], skT[4];
    float d_inter = 0.f, d_card = 0.f, d_st = 0.f;

    for (int phase = 0; phase < 2; ++phase) {
        // ---- load im0 (probs or float(target)) into bufA, +inf out-of-image ----
        for (int li = tid; li < NCELL; li += 256) {
            int r = li / IW, c = li - r * IW;
            int gy = y0 - HALO + r, gx = x0 - HALO + c;
            float v = INFINITY;
            if ((unsigned)gy < HH && (unsigned)gx < WW) {
                size_t g = (size_t)img * HW + (size_t)gy * WW + gx;
                if (phase == 0) {
                    float x = logits[g];
                    v = 1.0f / (1.0f + expf(-x));
                } else {
                    v = (float)target[g];
                }
            }
            bufA[li] = v;
        }
        __syncthreads();

        // ---- skel init: skel = relu(im0 - dilate(erode(im0))) ----
        erode_inner(bufA, bufB, y0, x0);
        __syncthreads();
        float sk[4], delta[4];
        open_delta(bufB, bufA, orow, oc, delta);
        const float* imr = bufA + (HALO + orow) * IW + (HALO + oc);
#pragma unroll
        for (int k = 0; k < 4; ++k) {
            float val = imr[k];
            sk[k] = delta[k];
            if (phase == 0) {
                p4[k] = val;
            } else {
                d_inter += p4[k] * val;
                d_card += p4[k] + val;
                d_st += val;
            }
        }

        // ---- 10 fused iterations ----
        float* cur = bufA;  // holds im_{it-1}
        float* oth = bufB;  // scratch
        for (int it = 1; it <= NITER; ++it) {
            __syncthreads();  // protect prior reads of oth before overwrite
            erode_shrink(cur, oth, it, y0, x0);  // oth = im_it (valid tile+(12-it))
            __syncthreads();
            erode_inner(oth, cur, y0, x0);       // cur = erode(im_it) on tile+1
            __syncthreads();
            open_delta(cur, oth, orow, oc, delta);
#pragma unroll
            for (int k = 0; k < 4; ++k) sk[k] += fmaxf(delta[k] - sk[k] * delta[k], 0.0f);
            float* t = cur; cur = oth; oth = t;  // im_it now in "cur"
        }
#pragma unroll
        for (int k = 0; k < 4; ++k) {
            if (phase == 0) skO[k] = sk[k]; else skT[k] = sk[k];
        }
        __syncthreads();  // before next phase load overwrites buffers
    }

    // ---- cldice per-thread sums ----
    float I = 0.f, So = 0.f, St = 0.f;
#pragma unroll
    for (int k = 0; k < 4; ++k) {
        I += skO[k] * skT[k];
        So += skO[k];
        St += skT[k];
    }

    // ---- block reduce 6 values ----
    float v6[6] = {d_inter, d_card, d_st, I, So, St};
#pragma unroll
    for (int q = 0; q < 6; ++q)
        for (int off = 32; off > 0; off >>= 1) v6[q] += __shfl_down(v6[q], off);
    int lane = tid & 63, w = tid >> 6;
    if (lane == 0) {
#pragma unroll
        for (int q = 0; q < 6; ++q) red[w * 6 + q] = v6[q];
    }
    __syncthreads();
    if (tid == 0) {
        int bid = (blockIdx.z * gridDim.y + blockIdx.y) * gridDim.x + blockIdx.x;
#pragma unroll
        for (int q = 0; q < 6; ++q)
            partials[q * NBLK + bid] = red[q] + red[6 + q] + red[12 + q] + red[18 + q];
    }
}

__global__ __launch_bounds__(256) void final_kernel(const float* __restrict__ partials,
                                                    float* __restrict__ out) {
    float s[6] = {0.f, 0.f, 0.f, 0.f, 0.f, 0.f};
    for (int i = threadIdx.x; i < NBLK; i += 256) {
#pragma unroll
        for (int q = 0; q < 6; ++q) s[q] += partials[q * NBLK + i];
    }
#pragma unroll
    for (int q = 0; q < 6; ++q)
        for (int off = 32; off > 0; off >>= 1) s[q] += __shfl_down(s[q], off);
    __shared__ float red[24];
    int lane = threadIdx.x & 63, w = threadIdx.x >> 6;
    if (lane == 0) {
#pragma unroll
        for (int q = 0; q < 6; ++q) red[w * 6 + q] = s[q];
    }
    __syncthreads();
    if (threadIdx.x == 0) {
        float inter = red[0] + red[6] + red[12] + red[18];
        float card  = red[1] + red[7] + red[13] + red[19];
        float sumt  = red[2] + red[8] + red[14] + red[20];
        float I     = red[3] + red[9] + red[15] + red[21];
        float So    = red[4] + red[10] + red[16] + red[22];
        float St    = red[5] + red[11] + red[17] + red[23];
        float score_d = (2.0f * inter + 1.0f) / fmaxf(card + 1.0f, 1e-7f);
        float dice = (1.0f - score_d) * (sumt > 0.0f ? 1.0f : 0.0f);
        float tprec = (I + 1.0f) / (So + 1.0f);
        float tsens = (I + 1.0f) / (St + 1.0f);
        float score_c = 2.0f * (tprec * tsens) / (tprec + tsens);
        float cl = (1.0f - score_c) * (St > 0.0f ? 1.0f : 0.0f);
        out[0] = 0.5f * dice + 0.5f * cl;
    }
}

extern "C" void kernel_launch(void* const* d_in, const int* in_sizes, int n_in,
                              void* d_out, int out_size, void* d_ws, size_t ws_size,
                              hipStream_t stream) {
    const float* logits = (const float*)d_in[0];
    const int* target = (const int*)d_in[1];
    float* out = (float*)d_out;
    float* partials = (float*)d_ws;  // 6*NBLK floats = 196 KB, fully overwritten

    dim3 grid(NBX, NBY, BATCH);
    cldice_mega_kernel<<<grid, 256, 0, stream>>>(logits, target, partials);
    final_kernel<<<1, 256, 0, stream>>>(partials, out);
}

// Round 4
// 667.932 us; speedup vs baseline: 1.1932x; 1.1932x over previous
//
#include <hip/hip_runtime.h>
#include <math.h>

// clDice loss, fully fused (R4: float4-vectorized LDS morphology).
// R3 postmortem: VALU-issue-bound (84% VALUBusy) on per-cell div/mod, per-iter
// bounds checks, scalar ds_read_b32, + 9.8e7 LDS bank conflicts.
// R4: float4 LDS cells (ds_read_b128, conflict-free), all iteration-invariant
// state (offsets, OOB masks, shrink bound M) precomputed into registers.
// OOB handling: masks folded in as fmax(v,+/-inf) -> single op, no branches.
// Shrink-cone: cell computed iff it <= M, M = min(r,39-r,4c+3,87-4c);
// stale cells are outside the dependency cone (erode reads inward only).

#define HH 1024
#define WW 1024
#define BATCH 8
#define HW (HH * WW)
#define NITER 10
#define TW 64
#define TH 16
#define HALO 12
#define IW 88
#define IH 40
#define IW4 22               // f4 cells per row
#define NCELL4 (IH * IW4)    // 880
#define E1N (38 * IW4)       // 836: e1 region rows 1..38, all 22 f4 cols
#define E2N (18 * 18)        // 324: e2 region rows 11..28, f4 cols 2..19
#define NBX (WW / TW)        // 16
#define NBY (HH / TH)        // 64
#define NBLK (NBX * NBY * BATCH)  // 8192

__device__ __forceinline__ float4 f4min5(const float4* __restrict__ b, int off) {
    float4 A = b[off - 1], B = b[off], C = b[off + 1];
    float4 U = b[off - IW4], D = b[off + IW4];
    float4 r;
    r.x = fminf(fminf(fminf(A.w, B.y), B.x), fminf(U.x, D.x));
    r.y = fminf(fminf(fminf(B.x, B.z), B.y), fminf(U.y, D.y));
    r.z = fminf(fminf(fminf(B.y, B.w), B.z), fminf(U.z, D.z));
    r.w = fminf(fminf(fminf(B.z, C.x), B.w), fminf(U.w, D.w));
    return r;
}
__device__ __forceinline__ float4 fmax4c(float4 a, float4 m) {
    return make_float4(fmaxf(a.x, m.x), fmaxf(a.y, m.y), fmaxf(a.z, m.z), fmaxf(a.w, m.w));
}
__device__ __forceinline__ float4 fmin4c(float4 a, float4 m) {
    return make_float4(fminf(a.x, m.x), fminf(a.y, m.y), fminf(a.z, m.z), fminf(a.w, m.w));
}
// 3x3 dilate at the 4 cells of f4 index base = r0*IW4+c4 (reads rows r0-1..r0+1)
__device__ __forceinline__ float4 open3x3(const float4* __restrict__ e, int base) {
    float4 a0 = e[base - IW4 - 1], b0 = e[base - IW4], c0 = e[base - IW4 + 1];
    float4 a1 = e[base - 1],       b1 = e[base],       c1 = e[base + 1];
    float4 a2 = e[base + IW4 - 1], b2 = e[base + IW4], c2 = e[base + IW4 + 1];
    float cm0 = fmaxf(fmaxf(a0.w, a1.w), a2.w);
    float Bx = fmaxf(fmaxf(b0.x, b1.x), b2.x);
    float By = fmaxf(fmaxf(b0.y, b1.y), b2.y);
    float Bz = fmaxf(fmaxf(b0.z, b1.z), b2.z);
    float Bw = fmaxf(fmaxf(b0.w, b1.w), b2.w);
    float cm5 = fmaxf(fmaxf(c0.x, c1.x), c2.x);
    float4 o;
    o.x = fmaxf(fmaxf(cm0, Bx), By);
    o.y = fmaxf(fmaxf(Bx, By), Bz);
    o.z = fmaxf(fmaxf(By, Bz), Bw);
    o.w = fmaxf(fmaxf(Bz, Bw), cm5);
    return o;
}
__device__ __forceinline__ float sigm(float x) { return 1.0f / (1.0f + __expf(-x)); }
__device__ __forceinline__ int imin(int a, int b) { return a < b ? a : b; }

__global__ __launch_bounds__(256) void cldice_mega_kernel(const float* __restrict__ logits,
                                                          const int* __restrict__ target,
                                                          float* __restrict__ partials) {
    __shared__ float4 bufA[NCELL4];
    __shared__ float4 bufB[NCELL4];
    __shared__ float red[24];

    const int tid = threadIdx.x;
    const int img = blockIdx.z;
    const int x0 = blockIdx.x * TW, y0 = blockIdx.y * TH;

    // ---- iteration-invariant precompute (registers) ----
    int e1_off[4], e1_M[4];
    float4 e1_m[4];
#pragma unroll
    for (int i = 0; i < 4; ++i) {
        int cell = tid + 256 * i;
        e1_M[i] = 0; e1_off[i] = 0;
        e1_m[i] = make_float4(-INFINITY, -INFINITY, -INFINITY, -INFINITY);
        if (cell < E1N) {
            int r = 1 + cell / IW4, c4 = cell % IW4;
            int cc = 4 * c4;
            e1_off[i] = r * IW4 + c4;
            e1_M[i] = imin(imin(r, 39 - r), imin(cc + 3, 87 - cc));
            int gy = y0 - HALO + r;
            bool gyok = (unsigned)gy < HH;
            int gx = x0 - HALO + cc;
            float4 m;
            m.x = (gyok && (unsigned)(gx + 0) < WW) ? -INFINITY : INFINITY;
            m.y = (gyok && (unsigned)(gx + 1) < WW) ? -INFINITY : INFINITY;
            m.z = (gyok && (unsigned)(gx + 2) < WW) ? -INFINITY : INFINITY;
            m.w = (gyok && (unsigned)(gx + 3) < WW) ? -INFINITY : INFINITY;
            e1_m[i] = m;
        }
    }
    int e2_off[2], e2_ok[2];
    float4 e2_m[2];
#pragma unroll
    for (int i = 0; i < 2; ++i) {
        int cell = tid + 256 * i;
        e2_ok[i] = 0; e2_off[i] = 0;
        e2_m[i] = make_float4(INFINITY, INFINITY, INFINITY, INFINITY);
        if (cell < E2N) {
            int r = 11 + cell / 18, c4 = 2 + cell % 18;
            int cc = 4 * c4;
            e2_off[i] = r * IW4 + c4;
            e2_ok[i] = 1;
            int gy = y0 - HALO + r;
            bool gyok = (unsigned)gy < HH;
            int gx = x0 - HALO + cc;
            float4 m;
            m.x = (gyok && (unsigned)(gx + 0) < WW) ? INFINITY : -INFINITY;
            m.y = (gyok && (unsigned)(gx + 1) < WW) ? INFINITY : -INFINITY;
            m.z = (gyok && (unsigned)(gx + 2) < WW) ? INFINITY : -INFINITY;
            m.w = (gyok && (unsigned)(gx + 3) < WW) ? INFINITY : -INFINITY;
            e2_m[i] = m;
        }
    }
    const int r0 = HALO + (tid >> 4);        // 12..27: my tile row
    const int c4d = 3 + (tid & 15);          // f4 col 3..18 (elements 12..75)
    const int offd = r0 * IW4 + c4d;

    float4 p4 = make_float4(0, 0, 0, 0), skO = make_float4(0, 0, 0, 0);
    float4 sk = make_float4(0, 0, 0, 0);
    float d_inter = 0.f, d_card = 0.f, d_st = 0.f;

    for (int phase = 0; phase < 2; ++phase) {
        // ---- load tile+halo into bufA (+inf out-of-image) ----
#pragma unroll
        for (int i = 0; i < 4; ++i) {
            int cell = tid + 256 * i;
            if (cell < NCELL4) {
                int r = cell / IW4, c4 = cell % IW4;
                int gy = y0 - HALO + r, gx = x0 - HALO + 4 * c4;
                bool gyok = (unsigned)gy < HH;
                float4 v;
                if (gyok && gx >= 0 && gx + 3 < WW) {
                    int g = img * HW + gy * WW + gx;
                    if (phase == 0) {
                        float4 x = *(const float4*)(logits + g);
                        v = make_float4(sigm(x.x), sigm(x.y), sigm(x.z), sigm(x.w));
                    } else {
                        int4 t = *(const int4*)(target + g);
                        v = make_float4((float)t.x, (float)t.y, (float)t.z, (float)t.w);
                    }
                } else {
                    float c[4];
#pragma unroll
                    for (int j = 0; j < 4; ++j) {
                        int gxx = gx + j;
                        if (gyok && (unsigned)gxx < WW) {
                            int g = img * HW + gy * WW + gxx;
                            c[j] = (phase == 0) ? sigm(logits[g]) : (float)target[g];
                        } else c[j] = INFINITY;
                    }
                    v = make_float4(c[0], c[1], c[2], c[3]);
                }
                bufA[cell] = v;
            }
        }
        __syncthreads();

        // ---- dice sums at my tile cells (bufA untouched yet) ----
        float4 v0 = bufA[offd];
        if (phase == 0) {
            p4 = v0;
        } else {
            d_inter += p4.x * v0.x + p4.y * v0.y + p4.z * v0.z + p4.w * v0.w;
            d_card += (p4.x + v0.x) + (p4.y + v0.y) + (p4.z + v0.z) + (p4.w + v0.w);
            d_st += v0.x + v0.y + v0.z + v0.w;
        }

        // ---- skel init: erode(im0) -> bufB ; sk = relu(im0 - dilate(bufB)) ----
#pragma unroll
        for (int i = 0; i < 2; ++i)
            if (e2_ok[i]) {
                float4 e = f4min5(bufA, e2_off[i]);
                bufB[e2_off[i]] = fmin4c(e, e2_m[i]);
            }
        __syncthreads();
        {
            float4 open = open3x3(bufB, offd);
            sk.x = fmaxf(v0.x - open.x, 0.f);
            sk.y = fmaxf(v0.y - open.y, 0.f);
            sk.z = fmaxf(v0.z - open.z, 0.f);
            sk.w = fmaxf(v0.w - open.w, 0.f);
        }

        // ---- 10 fused iterations ----
        float4* cur = bufA;
        float4* oth = bufB;
        for (int it = 1; it <= NITER; ++it) {
            __syncthreads();  // prior reads of oth done before e1 overwrites it
            // e1: im_it = erode(im_{it-1}) on shrinking cone
#pragma unroll
            for (int i = 0; i < 4; ++i)
                if (it <= e1_M[i]) {
                    float4 e = f4min5(cur, e1_off[i]);
                    oth[e1_off[i]] = fmax4c(e, e1_m[i]);
                }
            __syncthreads();
            // e2: erode(im_it) (feeds dilate; OOB -> -inf)
#pragma unroll
            for (int i = 0; i < 2; ++i)
                if (e2_ok[i]) {
                    float4 e = f4min5(oth, e2_off[i]);
                    cur[e2_off[i]] = fmin4c(e, e2_m[i]);
                }
            __syncthreads();
            // open + delta + skel update
            float4 open = open3x3(cur, offd);
            float4 im = oth[offd];
            float dx = fmaxf(im.x - open.x, 0.f);
            float dy = fmaxf(im.y - open.y, 0.f);
            float dz = fmaxf(im.z - open.z, 0.f);
            float dw = fmaxf(im.w - open.w, 0.f);
            sk.x += fmaxf(dx - sk.x * dx, 0.f);
            sk.y += fmaxf(dy - sk.y * dy, 0.f);
            sk.z += fmaxf(dz - sk.z * dz, 0.f);
            sk.w += fmaxf(dw - sk.w * dw, 0.f);
            float4* t = cur; cur = oth; oth = t;
        }
        if (phase == 0) skO = sk;
        __syncthreads();  // before next phase load overwrites bufA
    }

    // ---- cldice per-thread sums ----
    float I = skO.x * sk.x + skO.y * sk.y + skO.z * sk.z + skO.w * sk.w;
    float So = skO.x + skO.y + skO.z + skO.w;
    float St = sk.x + sk.y + sk.z + sk.w;

    // ---- block reduce 6 values ----
    float v6[6] = {d_inter, d_card, d_st, I, So, St};
#pragma unroll
    for (int q = 0; q < 6; ++q)
        for (int off = 32; off > 0; off >>= 1) v6[q] += __shfl_down(v6[q], off);
    int lane = tid & 63, w = tid >> 6;
    if (lane == 0) {
#pragma unroll
        for (int q = 0; q < 6; ++q) red[w * 6 + q] = v6[q];
    }
    __syncthreads();
    if (tid == 0) {
        int bid = (blockIdx.z * gridDim.y + blockIdx.y) * gridDim.x + blockIdx.x;
#pragma unroll
        for (int q = 0; q < 6; ++q)
            partials[q * NBLK + bid] = red[q] + red[6 + q] + red[12 + q] + red[18 + q];
    }
}

__global__ __launch_bounds__(256) void final_kernel(const float* __restrict__ partials,
                                                    float* __restrict__ out) {
    float s[6] = {0.f, 0.f, 0.f, 0.f, 0.f, 0.f};
    for (int i = threadIdx.x; i < NBLK; i += 256) {
#pragma unroll
        for (int q = 0; q < 6; ++q) s[q] += partials[q * NBLK + i];
    }
#pragma unroll
    for (int q = 0; q < 6; ++q)
        for (int off = 32; off > 0; off >>= 1) s[q] += __shfl_down(s[q], off);
    __shared__ float red[24];
    int lane = threadIdx.x & 63, w = threadIdx.x >> 6;
    if (lane == 0) {
#pragma unroll
        for (int q = 0; q < 6; ++q) red[w * 6 + q] = s[q];
    }
    __syncthreads();
    if (threadIdx.x == 0) {
        float inter = red[0] + red[6] + red[12] + red[18];
        float card  = red[1] + red[7] + red[13] + red[19];
        float sumt  = red[2] + red[8] + red[14] + red[20];
        float I     = red[3] + red[9] + red[15] + red[21];
        float So    = red[4] + red[10] + red[16] + red[22];
        float St    = red[5] + red[11] + red[17] + red[23];
        float score_d = (2.0f * inter + 1.0f) / fmaxf(card + 1.0f, 1e-7f);
        float dice = (1.0f - score_d) * (sumt > 0.0f ? 1.0f : 0.0f);
        float tprec = (I + 1.0f) / (So + 1.0f);
        float tsens = (I + 1.0f) / (St + 1.0f);
        float score_c = 2.0f * (tprec * tsens) / (tprec + tsens);
        float cl = (1.0f - score_c) * (St > 0.0f ? 1.0f : 0.0f);
        out[0] = 0.5f * dice + 0.5f * cl;
    }
}

extern "C" void kernel_launch(void* const* d_in, const int* in_sizes, int n_in,
                              void* d_out, int out_size, void* d_ws, size_t ws_size,
                              hipStream_t stream) {
    const float* logits = (const float*)d_in[0];
    const int* target = (const int*)d_in[1];
    float* out = (float*)d_out;
    float* partials = (float*)d_ws;  // 6*NBLK floats, fully overwritten each call

    dim3 grid(NBX, NBY, BATCH);
    cldice_mega_kernel<<<grid, 256, 0, stream>>>(logits, target, partials);
    final_kernel<<<1, 256, 0, stream>>>(partials, out);
}

// Round 6
// 415.154 us; speedup vs baseline: 1.9198x; 1.6089x over previous
//
#include <hip/hip_runtime.h>
#include <math.h>

// clDice loss, fully fused, fp16-packed LDS morphology (R6 = R5 with
// clang-native _Float16 vectors; ROCm has no __hmin2/__hmax2).
// R4 postmortem: LDS-bandwidth-bound (b128 throughput), so halve LDS
// instructions per pixel: 8 px per 16B cell, v_pk_min/max_f16 packed math.
// Morphology (min/max only) is EXACT in fp16; sigmoid quantization ~5e-4
// -> loss err ~1e-3 << 1.26e-2 threshold. Skel/dice accumulation in fp32.
// Validity-cone argument: element col j / row r is consumed at iter it only
// if inside cone(it) = [it, 96-it) x [it, 56-it); erode reads inward, so
// stale/garbage cells outside the cone never reach consumed outputs.

#define HH 1024
#define WW 1024
#define BATCH 8
#define HW (HH * WW)
#define NITER 10
#define TW 64
#define TH 32
#define HALOY 12
#define HALOX 16            // 16 for 8-alignment (12 needed)
#define IW 96               // elements per row
#define IH 56               // rows
#define IWC 12              // h8 cells per row (96/8)
#define NCELL (IH * IWC)    // 672
#define E1N (54 * IWC)      // 648: rows 1..54, all 12 cells
#define E2N (34 * 10)       // 340: rows 11..44, cells 1..10
#define NBX (WW / TW)       // 16
#define NBY (HH / TH)       // 32
#define NBLK (NBX * NBY * BATCH)  // 4096

typedef _Float16 h8 __attribute__((ext_vector_type(8)));

#define MIN2(a, b) __builtin_elementwise_min(a, b)
#define MAX2(a, b) __builtin_elementwise_max(a, b)

// cross erosion (min over c,u,d,l,r) of 8 packed elements at cell off
__device__ __forceinline__ h8 erode5(const h8* __restrict__ b, int off) {
    h8 A = b[off - 1], B = b[off], C = b[off + 1];
    h8 U = b[off - IWC], D = b[off + IWC];
    h8 L = __builtin_shufflevector(A, B, 7, 8, 9, 10, 11, 12, 13, 14);
    h8 R = __builtin_shufflevector(B, C, 1, 2, 3, 4, 5, 6, 7, 8);
    return MIN2(MIN2(B, MIN2(L, R)), MIN2(U, D));
}
// 3x3 dilate of 8 packed elements at cell off
__device__ __forceinline__ h8 open3(const h8* __restrict__ e, int off) {
    h8 VA = MAX2(MAX2(e[off - IWC - 1], e[off - 1]), e[off + IWC - 1]);
    h8 VB = MAX2(MAX2(e[off - IWC],     e[off]),     e[off + IWC]);
    h8 VC = MAX2(MAX2(e[off - IWC + 1], e[off + 1]), e[off + IWC + 1]);
    h8 L = __builtin_shufflevector(VA, VB, 7, 8, 9, 10, 11, 12, 13, 14);
    h8 R = __builtin_shufflevector(VB, VC, 1, 2, 3, 4, 5, 6, 7, 8);
    return MAX2(MAX2(L, R), VB);
}
__device__ __forceinline__ float sigm(float x) { return 1.0f / (1.0f + __expf(-x)); }
__device__ __forceinline__ int imin(int a, int b) { return a < b ? a : b; }

__global__ __launch_bounds__(256) void cldice_mega_kernel(const float* __restrict__ logits,
                                                          const int* __restrict__ target,
                                                          float* __restrict__ partials) {
    __shared__ h8 bufA[NCELL];
    __shared__ h8 bufB[NCELL];
    __shared__ float red[24];

    const int tid = threadIdx.x;
    const int img = blockIdx.z;
    const int x0 = blockIdx.x * TW, y0 = blockIdx.y * TH;

    const _Float16 HIF = (_Float16)__builtin_inff();
    const _Float16 LOF = -HIF;

    // ---- iteration-invariant precompute (registers) ----
    int e1_off[3], e1_M[3];
    h8 e1_m[3];
#pragma unroll
    for (int i = 0; i < 3; ++i) {
        int cell = tid + 256 * i;
        e1_M[i] = 0; e1_off[i] = 0;
        e1_m[i] = HIF;
        if (cell < E1N) {
            int r = 1 + cell / IWC, c = cell % IWC;
            e1_off[i] = r * IWC + c;
            e1_M[i] = imin(imin(r, 55 - r), imin(8 * c + 7, 95 - 8 * c));
            int gy = y0 - HALOY + r;
            bool gyok = (unsigned)gy < HH;
            int gx = x0 - HALOX + 8 * c;
            h8 m;
#pragma unroll
            for (int j = 0; j < 8; ++j)
                m[j] = (gyok && (unsigned)(gx + j) < WW) ? LOF : HIF;  // MAX-identity in-img
            e1_m[i] = m;
        }
    }
    int e2_off[2], e2_ok[2];
    h8 e2_m[2];
#pragma unroll
    for (int i = 0; i < 2; ++i) {
        int cell = tid + 256 * i;
        e2_ok[i] = 0; e2_off[i] = 0;
        e2_m[i] = HIF;
        if (cell < E2N) {
            int r = 11 + cell / 10, c = 1 + cell % 10;
            e2_off[i] = r * IWC + c;
            e2_ok[i] = 1;
            int gy = y0 - HALOY + r;
            bool gyok = (unsigned)gy < HH;
            int gx = x0 - HALOX + 8 * c;
            h8 m;
#pragma unroll
            for (int j = 0; j < 8; ++j)
                m[j] = (gyok && (unsigned)(gx + j) < WW) ? HIF : LOF;  // MIN-identity in-img
            e2_m[i] = m;
        }
    }
    const int offd = (HALOY + (tid >> 3)) * IWC + 2 + (tid & 7);  // my 8-px tile cell

    h8 p8 = (_Float16)0;
    float sk[8], skO[8];
    float d_inter = 0.f, d_card = 0.f, d_st = 0.f;

    for (int phase = 0; phase < 2; ++phase) {
        // ---- load tile+halo into bufA (+inf out-of-image), packed fp16 ----
#pragma unroll
        for (int i = 0; i < 3; ++i) {
            int cell = tid + 256 * i;
            if (cell < NCELL) {
                int r = cell / IWC, c = cell - r * IWC;
                int gy = y0 - HALOY + r, gx = x0 - HALOX + 8 * c;
                bool gyok = (unsigned)gy < HH;
                float v[8];
                if (gyok && gx >= 0 && gx + 7 < WW) {
                    int g = img * HW + gy * WW + gx;
                    if (phase == 0) {
                        float4 a = *(const float4*)(logits + g);
                        float4 b = *(const float4*)(logits + g + 4);
                        v[0] = sigm(a.x); v[1] = sigm(a.y); v[2] = sigm(a.z); v[3] = sigm(a.w);
                        v[4] = sigm(b.x); v[5] = sigm(b.y); v[6] = sigm(b.z); v[7] = sigm(b.w);
                    } else {
                        int4 a = *(const int4*)(target + g);
                        int4 b = *(const int4*)(target + g + 4);
                        v[0] = (float)a.x; v[1] = (float)a.y; v[2] = (float)a.z; v[3] = (float)a.w;
                        v[4] = (float)b.x; v[5] = (float)b.y; v[6] = (float)b.z; v[7] = (float)b.w;
                    }
                } else {
#pragma unroll
                    for (int j = 0; j < 8; ++j) {
                        int gxx = gx + j;
                        if (gyok && (unsigned)gxx < WW) {
                            int g = img * HW + gy * WW + gxx;
                            v[j] = (phase == 0) ? sigm(logits[g]) : (float)target[g];
                        } else v[j] = INFINITY;
                    }
                }
                h8 hv;
#pragma unroll
                for (int j = 0; j < 8; ++j) hv[j] = (_Float16)v[j];
                bufA[cell] = hv;
            }
        }
        __syncthreads();

        // ---- dice sums at my 8 tile pixels ----
        h8 v0 = bufA[offd];
        if (phase == 0) {
            p8 = v0;
        } else {
#pragma unroll
            for (int j = 0; j < 8; ++j) {
                float p = (float)p8[j], t = (float)v0[j];
                d_inter += p * t;
                d_card += p + t;
                d_st += t;
            }
        }

        // ---- skel init: erode(im0) -> bufB ; sk = relu(im0 - dilate(bufB)) ----
#pragma unroll
        for (int i = 0; i < 2; ++i)
            if (e2_ok[i]) bufB[e2_off[i]] = MIN2(erode5(bufA, e2_off[i]), e2_m[i]);
        __syncthreads();
        {
            h8 open = open3(bufB, offd);
#pragma unroll
            for (int j = 0; j < 8; ++j)
                sk[j] = fmaxf((float)v0[j] - (float)open[j], 0.f);
        }

        // ---- 10 fused iterations ----
        h8* cur = bufA;
        h8* oth = bufB;
        for (int it = 1; it <= NITER; ++it) {
            __syncthreads();  // prior reads of oth complete before overwrite
#pragma unroll
            for (int i = 0; i < 3; ++i)
                if (it <= e1_M[i]) oth[e1_off[i]] = MAX2(erode5(cur, e1_off[i]), e1_m[i]);
            __syncthreads();
#pragma unroll
            for (int i = 0; i < 2; ++i)
                if (e2_ok[i]) cur[e2_off[i]] = MIN2(erode5(oth, e2_off[i]), e2_m[i]);
            __syncthreads();
            h8 open = open3(cur, offd);
            h8 im8 = oth[offd];
#pragma unroll
            for (int j = 0; j < 8; ++j) {
                float d = fmaxf((float)im8[j] - (float)open[j], 0.f);
                sk[j] += fmaxf(d - sk[j] * d, 0.f);
            }
            h8* t = cur; cur = oth; oth = t;
        }
        if (phase == 0) {
#pragma unroll
            for (int j = 0; j < 8; ++j) skO[j] = sk[j];
        }
        __syncthreads();  // before next phase load overwrites buffers
    }

    // ---- cldice per-thread sums ----
    float I = 0.f, So = 0.f, St = 0.f;
#pragma unroll
    for (int j = 0; j < 8; ++j) { I += skO[j] * sk[j]; So += skO[j]; St += sk[j]; }

    // ---- block reduce 6 values ----
    float v6[6] = {d_inter, d_card, d_st, I, So, St};
#pragma unroll
    for (int q = 0; q < 6; ++q)
        for (int off = 32; off > 0; off >>= 1) v6[q] += __shfl_down(v6[q], off);
    int lane = tid & 63, w = tid >> 6;
    if (lane == 0) {
#pragma unroll
        for (int q = 0; q < 6; ++q) red[w * 6 + q] = v6[q];
    }
    __syncthreads();
    if (tid == 0) {
        int bid = (blockIdx.z * gridDim.y + blockIdx.y) * gridDim.x + blockIdx.x;
#pragma unroll
        for (int q = 0; q < 6; ++q)
            partials[q * NBLK + bid] = red[q] + red[6 + q] + red[12 + q] + red[18 + q];
    }
}

__global__ __launch_bounds__(256) void final_kernel(const float* __restrict__ partials,
                                                    float* __restrict__ out) {
    float s[6] = {0.f, 0.f, 0.f, 0.f, 0.f, 0.f};
    for (int i = threadIdx.x; i < NBLK; i += 256) {
#pragma unroll
        for (int q = 0; q < 6; ++q) s[q] += partials[q * NBLK + i];
    }
#pragma unroll
    for (int q = 0; q < 6; ++q)
        for (int off = 32; off > 0; off >>= 1) s[q] += __shfl_down(s[q], off);
    __shared__ float red[24];
    int lane = threadIdx.x & 63, w = threadIdx.x >> 6;
    if (lane == 0) {
#pragma unroll
        for (int q = 0; q < 6; ++q) red[w * 6 + q] = s[q];
    }
    __syncthreads();
    if (threadIdx.x == 0) {
        float inter = red[0] + red[6] + red[12] + red[18];
        float card  = red[1] + red[7] + red[13] + red[19];
        float sumt  = red[2] + red[8] + red[14] + red[20];
        float I     = red[3] + red[9] + red[15] + red[21];
        float So    = red[4] + red[10] + red[16] + red[22];
        float St    = red[5] + red[11] + red[17] + red[23];
        float score_d = (2.0f * inter + 1.0f) / fmaxf(card + 1.0f, 1e-7f);
        float dice = (1.0f - score_d) * (sumt > 0.0f ? 1.0f : 0.0f);
        float tprec = (I + 1.0f) / (So + 1.0f);
        float tsens = (I + 1.0f) / (St + 1.0f);
        float score_c = 2.0f * (tprec * tsens) / (tprec + tsens);
        float cl = (1.0f - score_c) * (St > 0.0f ? 1.0f : 0.0f);
        out[0] = 0.5f * dice + 0.5f * cl;
    }
}

extern "C" void kernel_launch(void* const* d_in, const int* in_sizes, int n_in,
                              void* d_out, int out_size, void* d_ws, size_t ws_size,
                              hipStream_t stream) {
    const float* logits = (const float*)d_in[0];
    const int* target = (const int*)d_in[1];
    float* out = (float*)d_out;
    float* partials = (float*)d_ws;  // 6*NBLK floats, fully overwritten each call

    dim3 grid(NBX, NBY, BATCH);
    cldice_mega_kernel<<<grid, 256, 0, stream>>>(logits, target, partials);
    final_kernel<<<1, 256, 0, stream>>>(partials, out);
}

// Round 7
// 278.560 us; speedup vs baseline: 2.8612x; 1.4904x over previous
//
#include <hip/hip_runtime.h>
#include <math.h>

// clDice loss, fully fused, fp16-packed LDS morphology (R7).
// R6 postmortem: VALU 54% / LDS ~45% / 66 barriers -> structure-bound.
// R7: eliminate the e2 (erode-for-dilate) pass. On in-image cells,
// erode(im_it) [-inf OOB, feeds dilate] == im_{it+1} [+inf OOB, feeds erode].
// So run only the e1 chain (levels 1..11); delta_it = relu(im_it -
// open3(im_{it+1})), with im_it carried in a register. Interior blocks (82%)
// use plain open3; border blocks apply row-selects + column masks inside the
// open to realize the -inf OOB semantics. 2 barriers/round (was 3), ~27%
// fewer LDS ops.
// Validity cone: element (r,j) of level L is consumed only if
// L <= min(r,55-r,j,95-j); erode reads inward, so stale cells outside the
// cone never reach consumed outputs. open3 at L<=11 needs rows 11..44,
// elements 15..80 -- inside the cone for all 11 levels.

#define HH 1024
#define WW 1024
#define BATCH 8
#define HW (HH * WW)
#define NITER 10
#define TW 64
#define TH 32
#define HALOY 12
#define HALOX 16            // 16 for 8-alignment (12 needed)
#define IW 96               // elements per row
#define IH 56               // rows
#define IWC 12              // h8 cells per row (96/8)
#define NCELL (IH * IWC)    // 672
#define E1N (54 * IWC)      // 648: rows 1..54, all 12 cells
#define NBX (WW / TW)       // 16
#define NBY (HH / TH)       // 32
#define NBLK (NBX * NBY * BATCH)  // 4096

typedef _Float16 h8 __attribute__((ext_vector_type(8)));

#define MIN2(a, b) __builtin_elementwise_min(a, b)
#define MAX2(a, b) __builtin_elementwise_max(a, b)

// cross erosion (min over c,u,d,l,r) of 8 packed elements at cell off
__device__ __forceinline__ h8 erode5(const h8* __restrict__ b, int off) {
    h8 A = b[off - 1], B = b[off], C = b[off + 1];
    h8 U = b[off - IWC], D = b[off + IWC];
    h8 L = __builtin_shufflevector(A, B, 7, 8, 9, 10, 11, 12, 13, 14);
    h8 R = __builtin_shufflevector(B, C, 1, 2, 3, 4, 5, 6, 7, 8);
    return MIN2(MIN2(B, MIN2(L, R)), MIN2(U, D));
}
// 3x3 dilate of 8 packed elements at cell off (aperture fully in-image)
__device__ __forceinline__ h8 open3(const h8* __restrict__ e, int off) {
    h8 VA = MAX2(MAX2(e[off - IWC - 1], e[off - 1]), e[off + IWC - 1]);
    h8 VB = MAX2(MAX2(e[off - IWC],     e[off]),     e[off + IWC]);
    h8 VC = MAX2(MAX2(e[off - IWC + 1], e[off + 1]), e[off + IWC + 1]);
    h8 L = __builtin_shufflevector(VA, VB, 7, 8, 9, 10, 11, 12, 13, 14);
    h8 R = __builtin_shufflevector(VB, VC, 1, 2, 3, 4, 5, 6, 7, 8);
    return MAX2(MAX2(L, R), VB);
}
__device__ __forceinline__ float sigm(float x) { return 1.0f / (1.0f + __expf(-x)); }
__device__ __forceinline__ int imin(int a, int b) { return a < b ? a : b; }

__global__ __launch_bounds__(256) void cldice_mega_kernel(const float* __restrict__ logits,
                                                          const int* __restrict__ target,
                                                          float* __restrict__ partials) {
    __shared__ h8 bufA[NCELL];
    __shared__ h8 bufB[NCELL];
    __shared__ float red[24];

    const int tid = threadIdx.x;
    const int img = blockIdx.z;
    const int x0 = blockIdx.x * TW, y0 = blockIdx.y * TH;

    const _Float16 HIF = (_Float16)__builtin_inff();
    const _Float16 LOF = -HIF;

    // ---- iteration-invariant precompute (registers) ----
    int e1_off[3], e1_M[3];
    h8 e1_m[3];
#pragma unroll
    for (int i = 0; i < 3; ++i) {
        int cell = tid + 256 * i;
        e1_M[i] = 0; e1_off[i] = 0;
        e1_m[i] = HIF;
        if (cell < E1N) {
            int r = 1 + cell / IWC, c = cell % IWC;
            e1_off[i] = r * IWC + c;
            e1_M[i] = imin(imin(r, 55 - r), imin(8 * c + 7, 95 - 8 * c));
            int gy = y0 - HALOY + r;
            bool gyok = (unsigned)gy < HH;
            int gx = x0 - HALOX + 8 * c;
            h8 m;
#pragma unroll
            for (int j = 0; j < 8; ++j)
                m[j] = (gyok && (unsigned)(gx + j) < WW) ? LOF : HIF;  // MAX-identity in-img
            e1_m[i] = m;
        }
    }
    const int ty = tid >> 3;                   // 0..31 tile row
    const int cx = 2 + (tid & 7);              // consumer cell col 2..9
    const int offd = (HALOY + ty) * IWC + cx;  // my 8-px tile cell

    // border-open machinery (only used when !fullin)
    const bool fullin = (x0 >= HALOX) && (x0 + TW + HALOX <= WW) &&
                        (y0 >= HALOY) && (y0 + TH + HALOY <= HH);
    const int gyc = y0 + ty;
    const bool up_ok = (gyc != 0);
    const bool dn_ok = (gyc != HH - 1);
    h8 mA, mC;  // column masks for cells cx-1, cx+1 (+inf in-img, -inf OOB)
#pragma unroll
    for (int j = 0; j < 8; ++j) {
        int ga = x0 - HALOX + 8 * (cx - 1) + j;
        int gc = x0 - HALOX + 8 * (cx + 1) + j;
        mA[j] = ((unsigned)ga < WW) ? HIF : LOF;
        mC[j] = ((unsigned)gc < WW) ? HIF : LOF;
    }

    h8 p8 = (_Float16)0;
    float sk[8], skO[8];
    float d_inter = 0.f, d_card = 0.f, d_st = 0.f;

    for (int phase = 0; phase < 2; ++phase) {
        // ---- load tile+halo into bufA (+inf out-of-image), packed fp16 ----
#pragma unroll
        for (int i = 0; i < 3; ++i) {
            int cell = tid + 256 * i;
            if (cell < NCELL) {
                int r = cell / IWC, c = cell - r * IWC;
                int gy = y0 - HALOY + r, gx = x0 - HALOX + 8 * c;
                bool gyok = (unsigned)gy < HH;
                float v[8];
                if (gyok && gx >= 0 && gx + 7 < WW) {
                    int g = img * HW + gy * WW + gx;
                    if (phase == 0) {
                        float4 a = *(const float4*)(logits + g);
                        float4 b = *(const float4*)(logits + g + 4);
                        v[0] = sigm(a.x); v[1] = sigm(a.y); v[2] = sigm(a.z); v[3] = sigm(a.w);
                        v[4] = sigm(b.x); v[5] = sigm(b.y); v[6] = sigm(b.z); v[7] = sigm(b.w);
                    } else {
                        int4 a = *(const int4*)(target + g);
                        int4 b = *(const int4*)(target + g + 4);
                        v[0] = (float)a.x; v[1] = (float)a.y; v[2] = (float)a.z; v[3] = (float)a.w;
                        v[4] = (float)b.x; v[5] = (float)b.y; v[6] = (float)b.z; v[7] = (float)b.w;
                    }
                } else {
#pragma unroll
                    for (int j = 0; j < 8; ++j) {
                        int gxx = gx + j;
                        if (gyok && (unsigned)gxx < WW) {
                            int g = img * HW + gy * WW + gxx;
                            v[j] = (phase == 0) ? sigm(logits[g]) : (float)target[g];
                        } else v[j] = INFINITY;
                    }
                }
                h8 hv;
#pragma unroll
                for (int j = 0; j < 8; ++j) hv[j] = (_Float16)v[j];
                bufA[cell] = hv;
            }
        }
        __syncthreads();

        // ---- dice sums at my 8 tile pixels ----
        h8 v0 = bufA[offd];
        if (phase == 0) {
            p8 = v0;
        } else {
#pragma unroll
            for (int j = 0; j < 8; ++j) {
                float p = (float)p8[j], t = (float)v0[j];
                d_inter += p * t;
                d_card += p + t;
                d_st += t;
            }
        }

        // ---- 11 fused passes: L produces im_L; delta_{L-1} from open3(im_L) ----
        h8* A = bufA;
        h8* B = bufB;
        h8 imv = v0;  // im_{L-1} at my tile cell
        for (int L = 1; L <= NITER + 1; ++L) {
            // e1: B = erode(A) on shrinking cone, +inf OOB
#pragma unroll
            for (int i = 0; i < 3; ++i)
                if (L <= e1_M[i]) B[e1_off[i]] = MAX2(erode5(A, e1_off[i]), e1_m[i]);
            __syncthreads();
            h8 open;
            if (fullin) {
                open = open3(B, offd);
            } else {
                const h8 NEG = (h8)LOF;
                h8 a0 = B[offd - IWC - 1], b0 = B[offd - IWC], c0 = B[offd - IWC + 1];
                h8 a1 = B[offd - 1],       b1 = B[offd],       c1 = B[offd + 1];
                h8 a2 = B[offd + IWC - 1], b2 = B[offd + IWC], c2 = B[offd + IWC + 1];
                if (!up_ok) { a0 = NEG; b0 = NEG; c0 = NEG; }
                if (!dn_ok) { a2 = NEG; b2 = NEG; c2 = NEG; }
                h8 VA = MIN2(MAX2(MAX2(a0, a1), a2), mA);
                h8 VB = MAX2(MAX2(b0, b1), b2);        // own columns always in-image
                h8 VC = MIN2(MAX2(MAX2(c0, c1), c2), mC);
                h8 Lh = __builtin_shufflevector(VA, VB, 7, 8, 9, 10, 11, 12, 13, 14);
                h8 Rh = __builtin_shufflevector(VB, VC, 1, 2, 3, 4, 5, 6, 7, 8);
                open = MAX2(MAX2(Lh, Rh), VB);
            }
            h8 imnew = B[offd];
#pragma unroll
            for (int j = 0; j < 8; ++j) {
                float d = fmaxf((float)imv[j] - (float)open[j], 0.f);
                if (L == 1) sk[j] = d;
                else sk[j] += fmaxf(d - sk[j] * d, 0.f);
            }
            imv = imnew;
            __syncthreads();  // all reads of A/B done before next pass overwrites
            h8* t = A; A = B; B = t;
        }
        if (phase == 0) {
#pragma unroll
            for (int j = 0; j < 8; ++j) skO[j] = sk[j];
        }
    }

    // ---- cldice per-thread sums ----
    float I = 0.f, So = 0.f, St = 0.f;
#pragma unroll
    for (int j = 0; j < 8; ++j) { I += skO[j] * sk[j]; So += skO[j]; St += sk[j]; }

    // ---- block reduce 6 values ----
    float v6[6] = {d_inter, d_card, d_st, I, So, St};
#pragma unroll
    for (int q = 0; q < 6; ++q)
        for (int off = 32; off > 0; off >>= 1) v6[q] += __shfl_down(v6[q], off);
    int lane = tid & 63, w = tid >> 6;
    if (lane == 0) {
#pragma unroll
        for (int q = 0; q < 6; ++q) red[w * 6 + q] = v6[q];
    }
    __syncthreads();
    if (tid == 0) {
        int bid = (blockIdx.z * gridDim.y + blockIdx.y) * gridDim.x + blockIdx.x;
#pragma unroll
        for (int q = 0; q < 6; ++q)
            partials[q * NBLK + bid] = red[q] + red[6 + q] + red[12 + q] + red[18 + q];
    }
}

__global__ __launch_bounds__(256) void final_kernel(const float* __restrict__ partials,
                                                    float* __restrict__ out) {
    float s[6] = {0.f, 0.f, 0.f, 0.f, 0.f, 0.f};
    for (int i = threadIdx.x; i < NBLK; i += 256) {
#pragma unroll
        for (int q = 0; q < 6; ++q) s[q] += partials[q * NBLK + i];
    }
#pragma unroll
    for (int q = 0; q < 6; ++q)
        for (int off = 32; off > 0; off >>= 1) s[q] += __shfl_down(s[q], off);
    __shared__ float red[24];
    int lane = threadIdx.x & 63, w = threadIdx.x >> 6;
    if (lane == 0) {
#pragma unroll
        for (int q = 0; q < 6; ++q) red[w * 6 + q] = s[q];
    }
    __syncthreads();
    if (threadIdx.x == 0) {
        float inter = red[0] + red[6] + red[12] + red[18];
        float card  = red[1] + red[7] + red[13] + red[19];
        float sumt  = red[2] + red[8] + red[14] + red[20];
        float I     = red[3] + red[9] + red[15] + red[21];
        float So    = red[4] + red[10] + red[16] + red[22];
        float St    = red[5] + red[11] + red[17] + red[23];
        float score_d = (2.0f * inter + 1.0f) / fmaxf(card + 1.0f, 1e-7f);
        float dice = (1.0f - score_d) * (sumt > 0.0f ? 1.0f : 0.0f);
        float tprec = (I + 1.0f) / (So + 1.0f);
        float tsens = (I + 1.0f) / (St + 1.0f);
        float score_c = 2.0f * (tprec * tsens) / (tprec + tsens);
        float cl = (1.0f - score_c) * (St > 0.0f ? 1.0f : 0.0f);
        out[0] = 0.5f * dice + 0.5f * cl;
    }
}

extern "C" void kernel_launch(void* const* d_in, const int* in_sizes, int n_in,
                              void* d_out, int out_size, void* d_ws, size_t ws_size,
                              hipStream_t stream) {
    const float* logits = (const float*)d_in[0];
    const int* target = (const int*)d_in[1];
    float* out = (float*)d_out;
    float* partials = (float*)d_ws;  // 6*NBLK floats, fully overwritten each call

    dim3 grid(NBX, NBY, BATCH);
    cldice_mega_kernel<<<grid, 256, 0, stream>>>(logits, target, partials);
    final_kernel<<<1, 256, 0, stream>>>(partials, out);
}

// Round 8
// 263.504 us; speedup vs baseline: 3.0246x; 1.0571x over previous
//
#include <hip/hip_runtime.h>
#include <math.h>

// clDice loss, fully fused, fp16-packed LDS morphology (R8).
// R7 postmortem: VALU 79% (skel update in scalar fp32 = ~20% of VALU),
// halo redundancy 2.625x, border mask applied even for interior blocks.
// R8: (1) skel/delta update in packed fp16 (h8 vector ops) -- loss is a
// ratio of 8.4M-px sums, fp16 error ~5e-4 washes out (threshold 1.26e-2);
// (2) tile 128x32, 512 threads: aperture 160x56, redundancy 2.19x (was
// 2.625x), e1-active cells/thread avg 1.67 (was 2.53); (3) interior blocks
// (70%) skip the e1 OOB mask; (4) final reduce with 1024 threads.
// Validity cone: element (r,j) of level L consumed only if
// L <= min(r,55-r,j,159-j); open3 at L<=11 touches rows 11..44, elements
// 15..144 (only elem 7 of edge cells survives the shuffle) -- in-cone.

#define HH 1024
#define WW 1024
#define BATCH 8
#define HW (HH * WW)
#define NITER 10
#define TW 128
#define TH 32
#define HALOY 12
#define HALOX 16            // 16 for 8-alignment (12 needed)
#define IW 160              // elements per row
#define IH 56               // rows
#define IWC 20              // h8 cells per row (160/8)
#define NCELL (IH * IWC)    // 1120
#define E1N (54 * IWC)      // 1080: rows 1..54, all 20 cells
#define NT 512              // threads per block
#define NBX (WW / TW)       // 8
#define NBY (HH / TH)       // 32
#define NBLK (NBX * NBY * BATCH)  // 2048

typedef _Float16 h8 __attribute__((ext_vector_type(8)));

#define MIN2(a, b) __builtin_elementwise_min(a, b)
#define MAX2(a, b) __builtin_elementwise_max(a, b)

// cross erosion (min over c,u,d,l,r) of 8 packed elements at cell off
__device__ __forceinline__ h8 erode5(const h8* __restrict__ b, int off) {
    h8 A = b[off - 1], B = b[off], C = b[off + 1];
    h8 U = b[off - IWC], D = b[off + IWC];
    h8 L = __builtin_shufflevector(A, B, 7, 8, 9, 10, 11, 12, 13, 14);
    h8 R = __builtin_shufflevector(B, C, 1, 2, 3, 4, 5, 6, 7, 8);
    return MIN2(MIN2(B, MIN2(L, R)), MIN2(U, D));
}
// 3x3 dilate at cell off (aperture fully in-image); also returns center.
__device__ __forceinline__ h8 open3(const h8* __restrict__ e, int off, h8* center) {
    h8 b1 = e[off];
    *center = b1;
    h8 VA = MAX2(MAX2(e[off - IWC - 1], e[off - 1]), e[off + IWC - 1]);
    h8 VB = MAX2(MAX2(e[off - IWC],     b1),         e[off + IWC]);
    h8 VC = MAX2(MAX2(e[off - IWC + 1], e[off + 1]), e[off + IWC + 1]);
    h8 L = __builtin_shufflevector(VA, VB, 7, 8, 9, 10, 11, 12, 13, 14);
    h8 R = __builtin_shufflevector(VB, VC, 1, 2, 3, 4, 5, 6, 7, 8);
    return MAX2(MAX2(L, R), VB);
}
__device__ __forceinline__ float sigm(float x) { return 1.0f / (1.0f + __expf(-x)); }
__device__ __forceinline__ int imin(int a, int b) { return a < b ? a : b; }

__global__ __launch_bounds__(NT) void cldice_mega_kernel(const float* __restrict__ logits,
                                                         const int* __restrict__ target,
                                                         float* __restrict__ partials) {
    __shared__ h8 bufA[NCELL];
    __shared__ h8 bufB[NCELL];
    __shared__ float red[48];

    const int tid = threadIdx.x;
    const int img = blockIdx.z;
    const int x0 = blockIdx.x * TW, y0 = blockIdx.y * TH;

    const _Float16 HIF = (_Float16)__builtin_inff();
    const _Float16 LOF = -HIF;
    const h8 Z8 = (h8)(_Float16)0;

    // ---- iteration-invariant precompute (registers) ----
    int e1_off[3], e1_M[3];
    h8 e1_m[3];
#pragma unroll
    for (int i = 0; i < 3; ++i) {
        int cell = tid + NT * i;
        e1_M[i] = 0; e1_off[i] = 0;
        e1_m[i] = HIF;
        if (cell < E1N) {
            int r = 1 + cell / IWC, c = cell % IWC;
            e1_off[i] = r * IWC + c;
            e1_M[i] = imin(imin(r, 55 - r), imin(8 * c + 7, 159 - 8 * c));
            int gy = y0 - HALOY + r;
            bool gyok = (unsigned)gy < HH;
            int gx = x0 - HALOX + 8 * c;
            h8 m;
#pragma unroll
            for (int j = 0; j < 8; ++j)
                m[j] = (gyok && (unsigned)(gx + j) < WW) ? LOF : HIF;  // MAX-identity in-img
            e1_m[i] = m;
        }
    }
    const int ty = tid >> 4;                   // 0..31 tile row
    const int cx = 2 + (tid & 15);             // consumer cell col 2..17
    const int offd = (HALOY + ty) * IWC + cx;  // my 8-px tile cell

    // border-open machinery (only used when !fullin)
    const bool fullin = (x0 >= HALOX) && (x0 + TW + HALOX <= WW) &&
                        (y0 >= HALOY) && (y0 + TH + HALOY <= HH);
    const int gyc = y0 + ty;
    const bool up_ok = (gyc != 0);
    const bool dn_ok = (gyc != HH - 1);
    h8 mA, mC;  // column masks for cells cx-1, cx+1 (+inf in-img, -inf OOB)
#pragma unroll
    for (int j = 0; j < 8; ++j) {
        int ga = x0 - HALOX + 8 * (cx - 1) + j;
        int gc = x0 - HALOX + 8 * (cx + 1) + j;
        mA[j] = ((unsigned)ga < WW) ? HIF : LOF;
        mC[j] = ((unsigned)gc < WW) ? HIF : LOF;
    }

    h8 p8 = Z8, sk = Z8, skO = Z8;
    float d_inter = 0.f, d_card = 0.f, d_st = 0.f;

    for (int phase = 0; phase < 2; ++phase) {
        // ---- load tile+halo into bufA (+inf out-of-image), packed fp16 ----
#pragma unroll
        for (int i = 0; i < 3; ++i) {
            int cell = tid + NT * i;
            if (cell < NCELL) {
                int r = cell / IWC, c = cell - r * IWC;
                int gy = y0 - HALOY + r, gx = x0 - HALOX + 8 * c;
                bool gyok = (unsigned)gy < HH;
                float v[8];
                if (gyok && gx >= 0 && gx + 7 < WW) {
                    int g = img * HW + gy * WW + gx;
                    if (phase == 0) {
                        float4 a = *(const float4*)(logits + g);
                        float4 b = *(const float4*)(logits + g + 4);
                        v[0] = sigm(a.x); v[1] = sigm(a.y); v[2] = sigm(a.z); v[3] = sigm(a.w);
                        v[4] = sigm(b.x); v[5] = sigm(b.y); v[6] = sigm(b.z); v[7] = sigm(b.w);
                    } else {
                        int4 a = *(const int4*)(target + g);
                        int4 b = *(const int4*)(target + g + 4);
                        v[0] = (float)a.x; v[1] = (float)a.y; v[2] = (float)a.z; v[3] = (float)a.w;
                        v[4] = (float)b.x; v[5] = (float)b.y; v[6] = (float)b.z; v[7] = (float)b.w;
                    }
                } else {
#pragma unroll
                    for (int j = 0; j < 8; ++j) {
                        int gxx = gx + j;
                        if (gyok && (unsigned)gxx < WW) {
                            int g = img * HW + gy * WW + gxx;
                            v[j] = (phase == 0) ? sigm(logits[g]) : (float)target[g];
                        } else v[j] = INFINITY;
                    }
                }
                h8 hv;
#pragma unroll
                for (int j = 0; j < 8; ++j) hv[j] = (_Float16)v[j];
                bufA[cell] = hv;
            }
        }
        __syncthreads();

        // ---- dice sums at my 8 tile pixels ----
        h8 v0 = bufA[offd];
        if (phase == 0) {
            p8 = v0;
        } else {
#pragma unroll
            for (int j = 0; j < 8; ++j) {
                float p = (float)p8[j], t = (float)v0[j];
                d_inter += p * t;
                d_card += p + t;
                d_st += t;
            }
        }

        // ---- 11 fused passes: L produces im_L; delta_{L-1} from open3(im_L) ----
        h8* A = bufA;
        h8* B = bufB;
        h8 imv = v0;  // im_{L-1} at my tile cell
        for (int L = 1; L <= NITER + 1; ++L) {
            // e1: B = erode(A) on shrinking cone, +inf OOB
            if (fullin) {
#pragma unroll
                for (int i = 0; i < 3; ++i)
                    if (L <= e1_M[i]) B[e1_off[i]] = erode5(A, e1_off[i]);
            } else {
#pragma unroll
                for (int i = 0; i < 3; ++i)
                    if (L <= e1_M[i]) B[e1_off[i]] = MAX2(erode5(A, e1_off[i]), e1_m[i]);
            }
            __syncthreads();
            h8 open, imnew;
            if (fullin) {
                open = open3(B, offd, &imnew);
            } else {
                const h8 NEG = (h8)LOF;
                h8 a0 = B[offd - IWC - 1], b0 = B[offd - IWC], c0 = B[offd - IWC + 1];
                h8 a1 = B[offd - 1],       b1 = B[offd],       c1 = B[offd + 1];
                h8 a2 = B[offd + IWC - 1], b2 = B[offd + IWC], c2 = B[offd + IWC + 1];
                imnew = b1;
                if (!up_ok) { a0 = NEG; b0 = NEG; c0 = NEG; }
                if (!dn_ok) { a2 = NEG; b2 = NEG; c2 = NEG; }
                h8 VA = MIN2(MAX2(MAX2(a0, a1), a2), mA);
                h8 VB = MAX2(MAX2(b0, b1), b2);        // own columns always in-image
                h8 VC = MIN2(MAX2(MAX2(c0, c1), c2), mC);
                h8 Lh = __builtin_shufflevector(VA, VB, 7, 8, 9, 10, 11, 12, 13, 14);
                h8 Rh = __builtin_shufflevector(VB, VC, 1, 2, 3, 4, 5, 6, 7, 8);
                open = MAX2(MAX2(Lh, Rh), VB);
            }
            // packed fp16 delta + skel update
            h8 d = MAX2(imv - open, Z8);
            if (L == 1) sk = d;
            else sk = sk + MAX2(d - sk * d, Z8);
            imv = imnew;
            __syncthreads();  // all reads of A/B done before next pass overwrites
            h8* t = A; A = B; B = t;
        }
        if (phase == 0) skO = sk;
    }

    // ---- cldice per-thread sums ----
    float I = 0.f, So = 0.f, St = 0.f;
#pragma unroll
    for (int j = 0; j < 8; ++j) {
        float a = (float)skO[j], b = (float)sk[j];
        I += a * b; So += a; St += b;
    }

    // ---- block reduce 6 values (8 waves) ----
    float v6[6] = {d_inter, d_card, d_st, I, So, St};
#pragma unroll
    for (int q = 0; q < 6; ++q)
        for (int off = 32; off > 0; off >>= 1) v6[q] += __shfl_down(v6[q], off);
    int lane = tid & 63, w = tid >> 6;
    if (lane == 0) {
#pragma unroll
        for (int q = 0; q < 6; ++q) red[w * 6 + q] = v6[q];
    }
    __syncthreads();
    if (tid == 0) {
        int bid = (blockIdx.z * gridDim.y + blockIdx.y) * gridDim.x + blockIdx.x;
#pragma unroll
        for (int q = 0; q < 6; ++q) {
            float s = 0.f;
#pragma unroll
            for (int ww = 0; ww < 8; ++ww) s += red[ww * 6 + q];
            partials[q * NBLK + bid] = s;
        }
    }
}

__global__ __launch_bounds__(1024) void final_kernel(const float* __restrict__ partials,
                                                     float* __restrict__ out) {
    float s[6] = {0.f, 0.f, 0.f, 0.f, 0.f, 0.f};
    for (int i = threadIdx.x; i < NBLK; i += 1024) {
#pragma unroll
        for (int q = 0; q < 6; ++q) s[q] += partials[q * NBLK + i];
    }
#pragma unroll
    for (int q = 0; q < 6; ++q)
        for (int off = 32; off > 0; off >>= 1) s[q] += __shfl_down(s[q], off);
    __shared__ float red[96];
    int lane = threadIdx.x & 63, w = threadIdx.x >> 6;
    if (lane == 0) {
#pragma unroll
        for (int q = 0; q < 6; ++q) red[w * 6 + q] = s[q];
    }
    __syncthreads();
    if (threadIdx.x == 0) {
        float t[6];
#pragma unroll
        for (int q = 0; q < 6; ++q) {
            float a = 0.f;
#pragma unroll
            for (int ww = 0; ww < 16; ++ww) a += red[ww * 6 + q];
            t[q] = a;
        }
        float inter = t[0], card = t[1], sumt = t[2];
        float I = t[3], So = t[4], St = t[5];
        float score_d = (2.0f * inter + 1.0f) / fmaxf(card + 1.0f, 1e-7f);
        float dice = (1.0f - score_d) * (sumt > 0.0f ? 1.0f : 0.0f);
        float tprec = (I + 1.0f) / (So + 1.0f);
        float tsens = (I + 1.0f) / (St + 1.0f);
        float score_c = 2.0f * (tprec * tsens) / (tprec + tsens);
        float cl = (1.0f - score_c) * (St > 0.0f ? 1.0f : 0.0f);
        out[0] = 0.5f * dice + 0.5f * cl;
    }
}

extern "C" void kernel_launch(void* const* d_in, const int* in_sizes, int n_in,
                              void* d_out, int out_size, void* d_ws, size_t ws_size,
                              hipStream_t stream) {
    const float* logits = (const float*)d_in[0];
    const int* target = (const int*)d_in[1];
    float* out = (float*)d_out;
    float* partials = (float*)d_ws;  // 6*NBLK floats, fully overwritten each call

    dim3 grid(NBX, NBY, BATCH);
    cldice_mega_kernel<<<grid, NT, 0, stream>>>(logits, target, partials);
    final_kernel<<<1, 1024, 0, stream>>>(partials, out);
}